// Round 8
// baseline (80.417 us; speedup 1.0000x reference)
//
#include <hip/hip_runtime.h>

// MultiLIF forward: B=32, L=2048, K=512. Fused producer/consumer kernel.
// 256 blocks x 512 threads (8 waves/CU, 1 block/CU, 64 chains/block):
//   wave 0    : serial LIF scan from LDS ring only; setprio(1).
//   waves 1-2 : DMA issuers, global_load_lds width-16 (1KB/instr) into an
//               8-chunk (64KB) ring; counted s_waitcnt vmcnt(24), never 0.
//   waves 3-7 : expanders. R8: dwordx4 nt stores -- lane l covers time-row
//               t = quad*4 + (l>>4), chains 4*(l&15)..+3, so one instruction
//               writes 1KB (4 full time-rows). Values stateless from packed
//               word: s=(bits>>t)&1, n=pbase+popc(bits&((2u<<t)-1)) (exact
//               small-int f32). Expanders never wait on vmcnt (stores from
//               many windows stay in flight; drained implicitly at endpgm).
// Two raw s_barriers per window (no __syncthreads -> no vmcnt(0) drain):
//   B_A: chunk w resident in LDS.  B_B: ring slot (w%8) free; packed[w&1]
//   visible to expanders at window w+1.
//
// Numerics (absmax 0, proven R5-R7): x/20, x/100 via split-constant fma
// (single rounding of x*(HI+LO), err ~2^-49 vs >=~2^-30 midpoint margin ->
// == IEEE division for all f32). th = 1 + 1.5*a separate mul+add (contract
// off). Spike select/reset exact; counts small ints, exact in f32.

#define LL 2048
#define KK 512

typedef float f4v __attribute__((ext_vector_type(4)));
typedef unsigned u4v __attribute__((ext_vector_type(4)));

constexpr int NCH = 8;        // ring depth (chunks)
constexpr int CH = 32;        // steps per chunk
constexpr int NWIN = LL / CH; // 64

constexpr float C20_HI = 0.05f;
constexpr float C20_LO = (float)(0.05 - (double)C20_HI);
constexpr float C100_HI = 0.01f;
constexpr float C100_LO = (float)(0.01 - (double)C100_HI);

__global__ __launch_bounds__(512, 1) void lif_fused(const float* __restrict__ I,
                                                    float* __restrict__ spikes,
                                                    float* __restrict__ series) {
#pragma clang fp contract(off)
    __shared__ float ring[NCH][CH][64];   // 64 KB
    __shared__ unsigned pbits[2][64];     // packed spikes handoff
    __shared__ float pbase[2][64];        // chunk-base running count

    const int tid = threadIdx.x;
    const int wid = tid >> 6;
    const int l = tid & 63;
    const int e0 = blockIdx.x * 64;       // first chain of this block
    const int b = e0 >> 9;
    const int k0 = e0 & 511;
    const size_t base = (size_t)b * LL * KK;

    if (wid == 1 || wid == 2) {
        // ---------------- DMA issuers ----------------
        const int j0 = (wid - 1) * 4;     // DMA quads j0..j0+3 of each chunk
        const float* g0 = I + base + (size_t)(l >> 4) * KK + (k0 + 4 * (l & 15));

        for (int c = 0; c < NCH - 1; ++c) {
#pragma unroll
            for (int jj = 0; jj < 4; ++jj) {
                const int j = j0 + jj;
                const float* g = g0 + (size_t)(c * CH + 4 * j) * KK;
                __builtin_amdgcn_global_load_lds(
                    (const __attribute__((address_space(1))) void*)g,
                    (__attribute__((address_space(3))) void*)&ring[c][4 * j][0],
                    16, 0, 0);
            }
        }
        for (int w = 0; w <= NWIN; ++w) {
            int c = w + NCH - 1;
            if (c > NWIN - 1) c = NWIN - 1;             // tail: clamped garbage
            const int slot = (w + NCH - 1) & (NCH - 1); // freed at B_B(w-1)
#pragma unroll
            for (int jj = 0; jj < 4; ++jj) {
                const int j = j0 + jj;
                const float* g = g0 + (size_t)(c * CH + 4 * j) * KK;
                __builtin_amdgcn_global_load_lds(
                    (const __attribute__((address_space(1))) void*)g,
                    (__attribute__((address_space(3))) void*)&ring[slot][4 * j][0],
                    16, 0, 0);
            }
            asm volatile("s_waitcnt vmcnt(24)" ::: "memory");
            asm volatile("s_barrier" ::: "memory");    // B_A
            asm volatile("s_barrier" ::: "memory");    // B_B
        }
    } else if (wid == 0) {
        // ---------------- consumer: serial scan ----------------
        __builtin_amdgcn_s_setprio(1);
        float v = 0.0f, a = 0.0f, n = 0.0f;
        for (int w = 0; w <= NWIN; ++w) {
            asm volatile("s_barrier" ::: "memory");    // B_A: chunk w resident
            if (w < NWIN) {
                const int slot = w & (NCH - 1);
                pbase[w & 1][l] = n;                   // count BEFORE chunk
                unsigned bits = 0;
                float cur[4], nxt[4];
#pragma unroll
                for (int i = 0; i < 4; ++i) cur[i] = ring[slot][i][l];
#pragma unroll
                for (int q = 0; q < 8; ++q) {
                    if (q < 7) {
#pragma unroll
                        for (int i = 0; i < 4; ++i)
                            nxt[i] = ring[slot][4 * q + 4 + i][l];
                    }
#pragma unroll
                    for (int i = 0; i < 4; ++i) {
                        const float It = cur[i];
                        const float d1 = __builtin_fmaf(v, C20_HI, v * C20_LO);
                        v = v - d1 + It;               // (v - v/20) + I_t
                        const float th = 1.0f + 1.5f * a;
                        const bool fired = (v >= th);
                        const float s1 = fired ? 1.0f : 0.0f;
                        n = n + s1;
                        v = fired ? -0.5f : v;         // exact reset select
                        const float d2 = __builtin_fmaf(a, C100_HI, a * C100_LO);
                        a = a - d2 + s1;               // (a - a/100) + s
                        bits |= (fired ? 1u : 0u) << (4 * q + i);
                    }
#pragma unroll
                    for (int i = 0; i < 4; ++i) cur[i] = nxt[i];
                }
                pbits[w & 1][l] = bits;
            }
            asm volatile("s_waitcnt lgkmcnt(0)" ::: "memory");
            asm volatile("s_barrier" ::: "memory");    // B_B
        }
    } else {
        // ---------------- expanders (wid 3..7): wide stateless expansion ----
        const int xi = wid - 3;                        // 0..4
        const int q0 = (xi < 3) ? xi * 2 : 6 + (xi - 3);
        const int nq = (xi < 3) ? 2 : 1;               // quads: 2,2,2,1,1
        const int kq = 4 * (l & 15);                   // chain quad this lane
        const int tr = l >> 4;                         // row within time-quad
        float* spb = spikes + base + (k0 + kq);
        float* ssb = series + base + (k0 + kq);
        for (int w = 0; w <= NWIN; ++w) {
            asm volatile("s_barrier" ::: "memory");    // B_A
            if (w >= 1) {
                const int c = w - 1;
                const u4v bb = *(const u4v*)&pbits[c & 1][kq];
                const f4v pb = *(const f4v*)&pbase[c & 1][kq];
                for (int qi = 0; qi < nq; ++qi) {
                    const int t = (q0 + qi) * 4 + tr;
                    const unsigned mask = (2u << t) - 1u;  // t=31 -> all ones
                    f4v vs, vn;
#pragma unroll
                    for (int j = 0; j < 4; ++j) {
                        vs[j] = (float)((bb[j] >> t) & 1u);
                        vn[j] = pb[j] + (float)__popc(bb[j] & mask);
                    }
                    const size_t off = (size_t)(c * CH + t) * KK;
                    __builtin_nontemporal_store(vs, (f4v*)(spb + off));
                    __builtin_nontemporal_store(vn, (f4v*)(ssb + off));
                }
            }
            asm volatile("s_barrier" ::: "memory");    // B_B
        }
    }
}

extern "C" void kernel_launch(void* const* d_in, const int* in_sizes, int n_in,
                              void* d_out, int out_size, void* d_ws, size_t ws_size,
                              hipStream_t stream) {
    const float* I = (const float*)d_in[0];
    float* spikes = (float*)d_out;
    float* series = (float*)d_out + (size_t)32 * LL * KK;
    lif_fused<<<256, 512, 0, stream>>>(I, spikes, series);
}

// Round 9
// 79.858 us; speedup vs baseline: 1.0070x; 1.0070x over previous
//
#include <hip/hip_runtime.h>

// MultiLIF forward: B=32, L=2048, K=512. Fused producer/consumer kernel, R9.
// 256 blocks x 704 threads (11 waves/CU, 1 block/CU, 64 chains/block):
//   wave 0    : serial LIF scan from LDS ring only; setprio(1).
//   waves 1-2 : DMA issuers, global_load_lds width-16 (1KB/instr), 8 per
//               window each, into a 5-chunk (80KB) ring; counted
//               s_waitcnt vmcnt(24) (chunks w+2..w+4 in flight), never 0.
//   waves 3-10: expanders, 2 time-quads each (16 quads = 64 rows/window),
//               dwordx4 nt stores, values stateless from packed bits.
// R9 vs R8: CH 32->64 (windows 64->32, barrier rounds 130->66), ring depth
// 256->320 steps, expander waves 5->8. Rationale: window pacer is the memory
// system (~24KB/window/CU ~= 2100cyc at the ~27 GB/s/CU fillBuffer rate);
// barrier skew and 1-window pipeline slack were the overhead; halve the
// rounds, deepen the slack.
//
// Barriers per window (raw s_barrier, never __syncthreads/vmcnt(0)):
//   B_A: chunk w resident in LDS.  B_B: ring slot (w%5) free for reuse;
//   packed[w&1] visible to expanders at window w+1.
//
// Numerics (absmax 0, proven R5-R8): x/20, x/100 via split-constant fma
// (single rounding of x*(HI+LO), err ~2^-49 vs >=~2^-30 midpoint margin ->
// == IEEE division for all f32). th = 1 + 1.5*a separate mul+add (contract
// off). Spike select/reset exact; counts small ints, exact in f32.

#define LL 2048
#define KK 512

typedef float f4v __attribute__((ext_vector_type(4)));
typedef unsigned u4v __attribute__((ext_vector_type(4)));

constexpr int CH = 64;          // steps per chunk/window
constexpr int NWIN = LL / CH;   // 32
constexpr int NCH = 5;          // ring chunks: 80 KB, 3-window read slack

constexpr float C20_HI = 0.05f;
constexpr float C20_LO = (float)(0.05 - (double)C20_HI);
constexpr float C100_HI = 0.01f;
constexpr float C100_LO = (float)(0.01 - (double)C100_HI);

__global__ __launch_bounds__(704, 1) void lif_fused(const float* __restrict__ I,
                                                    float* __restrict__ spikes,
                                                    float* __restrict__ series) {
#pragma clang fp contract(off)
    __shared__ float ring[NCH][CH][64];   // 80 KB
    __shared__ unsigned pbl[2][64];       // packed spike bits t=0..31
    __shared__ unsigned pbh[2][64];       // packed spike bits t=32..63
    __shared__ float pbase[2][64];        // chunk-base running count

    const int tid = threadIdx.x;
    const int wid = tid >> 6;
    const int l = tid & 63;
    const int e0 = blockIdx.x * 64;       // first chain of this block
    const int b = e0 >> 9;
    const int k0 = e0 & 511;
    const size_t base = (size_t)b * LL * KK;

    if (wid == 1 || wid == 2) {
        // ---------------- DMA issuers ----------------
        const int j0 = (wid - 1) * 8;     // time-quads j0..j0+7 of each chunk
        const float* g0 = I + base + (size_t)(l >> 4) * KK + (k0 + 4 * (l & 15));

        for (int c = 0; c < NCH - 1; ++c) {
#pragma unroll
            for (int jj = 0; jj < 8; ++jj) {
                const int j = j0 + jj;
                const float* g = g0 + (size_t)(c * CH + 4 * j) * KK;
                __builtin_amdgcn_global_load_lds(
                    (const __attribute__((address_space(1))) void*)g,
                    (__attribute__((address_space(3))) void*)&ring[c][4 * j][0],
                    16, 0, 0);
            }
        }
        for (int w = 0; w <= NWIN; ++w) {
            int c = w + NCH - 1;
            if (c > NWIN - 1) c = NWIN - 1;         // tail: clamped garbage
            const int slot = (w + NCH - 1) % NCH;   // freed at B_B(w-1)
#pragma unroll
            for (int jj = 0; jj < 8; ++jj) {
                const int j = j0 + jj;
                const float* g = g0 + (size_t)(c * CH + 4 * j) * KK;
                __builtin_amdgcn_global_load_lds(
                    (const __attribute__((address_space(1))) void*)g,
                    (__attribute__((address_space(3))) void*)&ring[slot][4 * j][0],
                    16, 0, 0);
            }
            // 5 chunks x8 outstanding after issue; keep 3 chunks (24):
            // chunks w and w+1 landed (margin 1)
            asm volatile("s_waitcnt vmcnt(24)" ::: "memory");
            asm volatile("s_barrier" ::: "memory");    // B_A
            asm volatile("s_barrier" ::: "memory");    // B_B
        }
    } else if (wid == 0) {
        // ---------------- consumer: serial scan ----------------
        __builtin_amdgcn_s_setprio(1);
        float v = 0.0f, a = 0.0f, n = 0.0f;
        for (int w = 0; w <= NWIN; ++w) {
            asm volatile("s_barrier" ::: "memory");    // B_A: chunk w resident
            if (w < NWIN) {
                const int slot = w % NCH;
                pbase[w & 1][l] = n;                   // count BEFORE chunk
                unsigned bl = 0, bh = 0;
                float cur[4], nxt[4];
#pragma unroll
                for (int i = 0; i < 4; ++i) cur[i] = ring[slot][i][l];
#pragma unroll
                for (int q = 0; q < 16; ++q) {
                    if (q < 15) {
#pragma unroll
                        for (int i = 0; i < 4; ++i)
                            nxt[i] = ring[slot][4 * q + 4 + i][l];
                    }
#pragma unroll
                    for (int i = 0; i < 4; ++i) {
                        const float It = cur[i];
                        const float d1 = __builtin_fmaf(v, C20_HI, v * C20_LO);
                        v = v - d1 + It;               // (v - v/20) + I_t
                        const float th = 1.0f + 1.5f * a;
                        const bool fired = (v >= th);
                        const float s1 = fired ? 1.0f : 0.0f;
                        n = n + s1;
                        v = fired ? -0.5f : v;         // exact reset select
                        const float d2 = __builtin_fmaf(a, C100_HI, a * C100_LO);
                        a = a - d2 + s1;               // (a - a/100) + s
                        const unsigned bit = fired ? 1u : 0u;
                        const int t = 4 * q + i;       // compile-time
                        if (t < 32) bl |= bit << t;
                        else        bh |= bit << (t - 32);
                    }
#pragma unroll
                    for (int i = 0; i < 4; ++i) cur[i] = nxt[i];
                }
                pbl[w & 1][l] = bl;
                pbh[w & 1][l] = bh;
            }
            asm volatile("s_waitcnt lgkmcnt(0)" ::: "memory");
            asm volatile("s_barrier" ::: "memory");    // B_B
        }
    } else {
        // ------------- expanders (wid 3..10): 2 time-quads each -------------
        const int xi = wid - 3;                        // 0..7
        const int kq = 4 * (l & 15);                   // chain quad this lane
        const int tr = l >> 4;                         // row within time-quad
        float* spb = spikes + base + (k0 + kq);
        float* ssb = series + base + (k0 + kq);
        for (int w = 0; w <= NWIN; ++w) {
            asm volatile("s_barrier" ::: "memory");    // B_A
            if (w >= 1) {
                const int c = w - 1;
                const int p = c & 1;
                const u4v lo = *(const u4v*)&pbl[p][kq];
                const u4v hi = *(const u4v*)&pbh[p][kq];
                const f4v pb = *(const f4v*)&pbase[p][kq];
#pragma unroll
                for (int qi = 0; qi < 2; ++qi) {
                    const int q = 2 * xi + qi;         // 0..15, wave-uniform
                    const int t = 4 * q + tr;
                    const bool sel = (q >= 8);
                    const int tt = t & 31;
                    const unsigned mask = (2u << tt) - 1u;  // tt=31 -> all ones
                    f4v vs, vn;
#pragma unroll
                    for (int j = 0; j < 4; ++j) {
                        const unsigned w32 = sel ? hi[j] : lo[j];
                        const float pre = sel ? (float)__popc(lo[j]) : 0.0f;
                        vs[j] = (float)((w32 >> tt) & 1u);
                        vn[j] = pb[j] + (pre + (float)__popc(w32 & mask));
                    }
                    const size_t off = (size_t)(c * CH + t) * KK;
                    __builtin_nontemporal_store(vs, (f4v*)(spb + off));
                    __builtin_nontemporal_store(vn, (f4v*)(ssb + off));
                }
            }
            asm volatile("s_barrier" ::: "memory");    // B_B
        }
    }
}

extern "C" void kernel_launch(void* const* d_in, const int* in_sizes, int n_in,
                              void* d_out, int out_size, void* d_ws, size_t ws_size,
                              hipStream_t stream) {
    const float* I = (const float*)d_in[0];
    float* spikes = (float*)d_out;
    float* series = (float*)d_out + (size_t)32 * LL * KK;
    lif_fused<<<256, 704, 0, stream>>>(I, spikes, series);
}